// Round 8
// baseline (272.480 us; speedup 1.0000x reference)
//
#include <hip/hip_runtime.h>

// Fused SSIM loss via MFMA separable blur (fp16 planes). B=32, C=1, 512x512.
// Blur = two banded matmuls, band A[m][k] = g[k-m] held in one fragment.
// 4 planes: p, t, s=p^2+t^2, q=p*t. Tile 64x16, 8192 blocks, ~32KB LDS
// -> 5 blocks/CU. rawT is XOR-swizzled (8B sub-chunks) so staging writes
// and pass-1 ds_read_b64 sit at the 32-bank structural floor (0 conflicts).
// Single dispatch: partial + ticket counter in d_ws (poison-start-agnostic:
// ((old+1) & 8191)==0 fires exactly once per launch for any start value).
typedef _Float16 f16x2 __attribute__((ext_vector_type(2)));
typedef _Float16 f16x4 __attribute__((ext_vector_type(4)));
typedef _Float16 f16x8 __attribute__((ext_vector_type(8)));
typedef float    f32x4 __attribute__((ext_vector_type(4)));

#define NBLK 8192    // 32 images * 8 x-tiles * 32 y-tiles

__device__ __forceinline__ f16x2 pkrtz(float a, float b) {
    return __builtin_bit_cast(f16x2, __builtin_amdgcn_cvt_pkrtz(a, b));
}

__global__ __launch_bounds__(256, 5)
void ssim_fused(const float* __restrict__ pred,
                const float* __restrict__ targ,
                const float* __restrict__ win,
                float* __restrict__ partial,
                unsigned int* __restrict__ cnt,
                float* __restrict__ out)
{
    // rawT: [plane][x:80][y:32 swizzled] fp16 = 20 KiB
    // vbuf: [plane][y:16][x: stride 88]  fp16 = 11 KiB
    __shared__ __align__(16) _Float16 rawT[4 * 80 * 32];
    __shared__ __align__(16) _Float16 vbuf[4 * 16 * 88];
    __shared__ float  gw[16];
    __shared__ float  wsum[4];
    __shared__ double dsum[4];
    __shared__ int    go;

    const int tid  = threadIdx.x;
    const int lane = tid & 63;
    const int wv   = tid >> 6;
    const int bid  = blockIdx.x;
    const int b    = bid >> 8;        // 256 tiles per image
    const int rem  = bid & 255;
    const int ty   = rem >> 3;        // 0..31
    const int tx   = rem & 7;         // 0..7
    const int x0g  = tx * 64 - 5;
    const int y0g  = ty * 16 - 5;

    // 1-D gaussian = row sums of the 2-D window (window sums to 1).
    if (tid < 11) {
        float s = 0.f;
        #pragma unroll
        for (int j = 0; j < 11; ++j) s += win[tid * 11 + j];
        gw[tid] = s;
    }

    const float* pb = pred + (size_t)b * (512 * 512);
    const float* tb = targ + (size_t)b * (512 * 512);
    const bool interior = (tx >= 1) & (tx <= 6) & (ty >= 1) & (ty <= 30);

    // ---- Stage raw^T planes (fp16, pkrtz), zero-pad outside (SAME). ----
    // 240 threads: x = tid%80, y-quads qy = r0, r0+3, ... (8 quads of 4 rows).
    // Swizzle: sub-chunk (4 halfwords) index sc' = qy ^ ((x>>1)&7).
    if (tid < 240) {
        const int x  = tid % 80;
        const int r0 = tid / 80;
        const int gx = x0g + x;
        const int sw = (x >> 1) & 7;
        const bool xok = (unsigned)gx < 512u;
        _Float16* rb = &rawT[x * 32];
        for (int qy = r0; qy < 8; qy += 3) {
            const int gy = y0g + qy * 4;
            float p0, p1, p2, p3, t0, t1, t2, t3;
            if (interior) {
                const float* pp = pb + (size_t)gy * 512 + gx;
                const float* tp = tb + (size_t)gy * 512 + gx;
                p0 = pp[0]; p1 = pp[512]; p2 = pp[1024]; p3 = pp[1536];
                t0 = tp[0]; t1 = tp[512]; t2 = tp[1024]; t3 = tp[1536];
            } else {
                p0 = p1 = p2 = p3 = t0 = t1 = t2 = t3 = 0.f;
                if (xok) {
                    const float* pp = pb + (size_t)gy * 512 + gx;
                    const float* tp = tb + (size_t)gy * 512 + gx;
                    if ((unsigned)(gy    ) < 512u) { p0 = pp[0];    t0 = tp[0];    }
                    if ((unsigned)(gy + 1) < 512u) { p1 = pp[512];  t1 = tp[512];  }
                    if ((unsigned)(gy + 2) < 512u) { p2 = pp[1024]; t2 = tp[1024]; }
                    if ((unsigned)(gy + 3) < 512u) { p3 = pp[1536]; t3 = tp[1536]; }
                }
            }
            const int off = (qy ^ sw) << 2;
            union { f16x2 h2[2]; f16x4 v; } u;
            u.h2[0] = pkrtz(p0, p1);
            u.h2[1] = pkrtz(p2, p3);
            *(f16x4*)&rb[off] = u.v;
            u.h2[0] = pkrtz(t0, t1);
            u.h2[1] = pkrtz(t2, t3);
            *(f16x4*)&rb[2560 + off] = u.v;
            u.h2[0] = pkrtz(fmaf(p0, p0, t0 * t0), fmaf(p1, p1, t1 * t1));
            u.h2[1] = pkrtz(fmaf(p2, p2, t2 * t2), fmaf(p3, p3, t3 * t3));
            *(f16x4*)&rb[5120 + off] = u.v;
            u.h2[0] = pkrtz(p0 * t0, p1 * t1);
            u.h2[1] = pkrtz(p2 * t2, p3 * t3);
            *(f16x4*)&rb[7680 + off] = u.v;
        }
    }
    __syncthreads();

    // ---- Band fragment A[m][k] = g[k-m] (m=lane&15, k=quad*8+j). ----
    const int mrow = lane & 15;
    const int quad = lane >> 4;
    f16x8 afr;
    #pragma unroll
    for (int j = 0; j < 8; ++j) {
        const int d = quad * 8 + j - mrow;
        afr[j] = (d >= 0 && d < 11) ? (_Float16)gw[d] : (_Float16)0.f;
    }
    const f32x4 z4 = {0.f, 0.f, 0.f, 0.f};

    // ---- Pass 1 (vertical): wave wv owns plane wv; 5 x-chunks. ----
    // V[m][x] = sum_k g[k-m] * raw[y=k][x];  B from swizzled rawT (2x b64).
    const int swr = mrow >> 1;           // (x>>1)&7 for x = 16c + mrow
    #pragma unroll
    for (int c = 0; c < 5; ++c) {
        const int x = c * 16 + mrow;
        const _Float16* base = &rawT[wv * 2560 + x * 32];
        union { f16x4 h[2]; f16x8 v; } bu;
        bu.h[0] = *(const f16x4*)&base[((2 * quad    ) ^ swr) << 2];
        bu.h[1] = *(const f16x4*)&base[((2 * quad + 1) ^ swr) << 2];
        const f32x4 dv = __builtin_amdgcn_mfma_f32_16x16x32_f16(afr, bu.v, z4, 0, 0, 0);
        #pragma unroll
        for (int r = 0; r < 4; ++r)
            vbuf[wv * 1408 + (quad * 4 + r) * 88 + x] = (_Float16)dv[r];
    }
    __syncthreads();

    // ---- Pass 2 (horizontal) + SSIM: wave wv owns x-tile X0 = 16*wv. ----
    float lsum = 0.f;
    {
        const int X0 = wv * 16;
        f32x4 dq[4];
        #pragma unroll
        for (int pl = 0; pl < 4; ++pl) {
            const f16x8 bv = *(const f16x8*)&vbuf[pl * 1408 + mrow * 88 + X0 + quad * 8];
            dq[pl] = __builtin_amdgcn_mfma_f32_16x16x32_f16(afr, bv, z4, 0, 0, 0);
        }
        #pragma unroll
        for (int r = 0; r < 4; ++r) {
            const float mp = dq[0][r], mt = dq[1][r];
            const float sv = dq[2][r], qv = dq[3][r];
            const float mp2 = mp * mp, mt2 = mt * mt, mpt = mp * mt;
            const float sig = fmaxf(sv - mp2 - mt2, 0.f);
            const float cv  = qv - mpt;
            const float num = (2.f * mpt + 1e-4f) * (2.f * cv + 9e-4f);
            const float den = (mp2 + mt2 + 1e-4f) * (sig + 9e-4f);
            lsum += num * __builtin_amdgcn_rcpf(den + 1e-8f);
        }
    }

    // ---- Block reduce, device-atomic partial, poison-agnostic ticket. ----
    #pragma unroll
    for (int off = 32; off > 0; off >>= 1)
        lsum += __shfl_down(lsum, off, 64);
    if (lane == 0) wsum[wv] = lsum;
    __syncthreads();
    if (tid == 0) {
        const float pblk = wsum[0] + wsum[1] + wsum[2] + wsum[3];
        atomicExch(&partial[bid], pblk);   // device-scope: visible at MALL
        __threadfence();                   // order exch before ticket
        const unsigned old = atomicAdd(cnt, 1u);
        go = (((old + 1u) & (unsigned)(NBLK - 1)) == 0u);  // exactly 1/launch
    }
    __syncthreads();
    if (go) {
        __threadfence();
        double s = 0.0;
        for (int i = tid; i < NBLK; i += 256)
            s += (double)atomicAdd(&partial[i], 0.0f);   // coherent read
        #pragma unroll
        for (int off = 32; off > 0; off >>= 1)
            s += __shfl_down(s, off, 64);
        if (lane == 0) dsum[wv] = s;
        __syncthreads();
        if (tid == 0) {
            const double tot = dsum[0] + dsum[1] + dsum[2] + dsum[3];
            out[0] = (float)(1.0 - tot / 8388608.0);
        }
    }
}

extern "C" void kernel_launch(void* const* d_in, const int* in_sizes, int n_in,
                              void* d_out, int out_size, void* d_ws, size_t ws_size,
                              hipStream_t stream)
{
    const float* pred = (const float*)d_in[0];
    const float* targ = (const float*)d_in[1];
    const float* win  = (const float*)d_in[2];
    float* out = (float*)d_out;
    float*        partial = (float*)d_ws;                       // 32 KiB
    unsigned int* cnt     = (unsigned int*)((char*)d_ws + NBLK * sizeof(float));

    ssim_fused<<<NBLK, 256, 0, stream>>>(pred, targ, win, partial, cnt, out);
}

// Round 9
// 115.422 us; speedup vs baseline: 2.3607x; 2.3607x over previous
//
#include <hip/hip_runtime.h>

// Fused SSIM loss via MFMA separable blur (fp16 planes). B=32, C=1, 512x512.
// Blur = two banded matmuls, band A[m][k] = g[k-m] held in one fragment.
// 4 planes: p, t, s=p^2+t^2, q=p*t. Tile 64x16, 8192 blocks, ~32KB LDS.
// rawT XOR-swizzled (8B sub-chunks) -> near-zero bank conflicts.
// Reduction: plain per-block partial store + tiny second kernel.
// (R8 lesson: 8192 same-address atomics + device fences cost ~200us.)
typedef _Float16 f16x2 __attribute__((ext_vector_type(2)));
typedef _Float16 f16x4 __attribute__((ext_vector_type(4)));
typedef _Float16 f16x8 __attribute__((ext_vector_type(8)));
typedef float    f32x4 __attribute__((ext_vector_type(4)));

#define NBLK 8192    // 32 images * 8 x-tiles * 32 y-tiles

__device__ __forceinline__ f16x2 pkrtz(float a, float b) {
    return __builtin_bit_cast(f16x2, __builtin_amdgcn_cvt_pkrtz(a, b));
}

__global__ __launch_bounds__(256, 5)
void ssim_fused(const float* __restrict__ pred,
                const float* __restrict__ targ,
                const float* __restrict__ win,
                float* __restrict__ partial)
{
    // rawT: [plane][x:80][y:32 swizzled] fp16 = 20 KiB
    // vbuf: [plane][y:16][x: stride 88]  fp16 = 11 KiB
    __shared__ __align__(16) _Float16 rawT[4 * 80 * 32];
    __shared__ __align__(16) _Float16 vbuf[4 * 16 * 88];
    __shared__ float gw[16];
    __shared__ float wsum[4];

    const int tid  = threadIdx.x;
    const int lane = tid & 63;
    const int wv   = tid >> 6;
    const int bid  = blockIdx.x;
    const int b    = bid >> 8;        // 256 tiles per image
    const int rem  = bid & 255;
    const int ty   = rem >> 3;        // 0..31
    const int tx   = rem & 7;         // 0..7
    const int x0g  = tx * 64 - 5;
    const int y0g  = ty * 16 - 5;

    // 1-D gaussian = row sums of the 2-D window (window sums to 1).
    if (tid < 11) {
        float s = 0.f;
        #pragma unroll
        for (int j = 0; j < 11; ++j) s += win[tid * 11 + j];
        gw[tid] = s;
    }

    const float* pb = pred + (size_t)b * (512 * 512);
    const float* tb = targ + (size_t)b * (512 * 512);
    const bool interior = (tx >= 1) & (tx <= 6) & (ty >= 1) & (ty <= 30);

    // ---- Stage raw^T planes (fp16, pkrtz), zero-pad outside (SAME). ----
    // 240 threads: x = tid%80, y-quads qy = r0, r0+3, ... (8 quads of 4 rows).
    // Swizzle: sub-chunk (4 halfwords) index sc' = qy ^ ((x>>1)&7).
    if (tid < 240) {
        const int x  = tid % 80;
        const int r0 = tid / 80;
        const int gx = x0g + x;
        const int sw = (x >> 1) & 7;
        const bool xok = (unsigned)gx < 512u;
        _Float16* rb = &rawT[x * 32];
        for (int qy = r0; qy < 8; qy += 3) {
            const int gy = y0g + qy * 4;
            float p0, p1, p2, p3, t0, t1, t2, t3;
            if (interior) {
                const float* pp = pb + (size_t)gy * 512 + gx;
                const float* tp = tb + (size_t)gy * 512 + gx;
                p0 = pp[0]; p1 = pp[512]; p2 = pp[1024]; p3 = pp[1536];
                t0 = tp[0]; t1 = tp[512]; t2 = tp[1024]; t3 = tp[1536];
            } else {
                p0 = p1 = p2 = p3 = t0 = t1 = t2 = t3 = 0.f;
                if (xok) {
                    const float* pp = pb + (size_t)gy * 512 + gx;
                    const float* tp = tb + (size_t)gy * 512 + gx;
                    if ((unsigned)(gy    ) < 512u) { p0 = pp[0];    t0 = tp[0];    }
                    if ((unsigned)(gy + 1) < 512u) { p1 = pp[512];  t1 = tp[512];  }
                    if ((unsigned)(gy + 2) < 512u) { p2 = pp[1024]; t2 = tp[1024]; }
                    if ((unsigned)(gy + 3) < 512u) { p3 = pp[1536]; t3 = tp[1536]; }
                }
            }
            const int off = (qy ^ sw) << 2;
            union { f16x2 h2[2]; f16x4 v; } u;
            u.h2[0] = pkrtz(p0, p1);
            u.h2[1] = pkrtz(p2, p3);
            *(f16x4*)&rb[off] = u.v;
            u.h2[0] = pkrtz(t0, t1);
            u.h2[1] = pkrtz(t2, t3);
            *(f16x4*)&rb[2560 + off] = u.v;
            u.h2[0] = pkrtz(fmaf(p0, p0, t0 * t0), fmaf(p1, p1, t1 * t1));
            u.h2[1] = pkrtz(fmaf(p2, p2, t2 * t2), fmaf(p3, p3, t3 * t3));
            *(f16x4*)&rb[5120 + off] = u.v;
            u.h2[0] = pkrtz(p0 * t0, p1 * t1);
            u.h2[1] = pkrtz(p2 * t2, p3 * t3);
            *(f16x4*)&rb[7680 + off] = u.v;
        }
    }
    __syncthreads();

    // ---- Band fragment A[m][k] = g[k-m] (m=lane&15, k=quad*8+j). ----
    const int mrow = lane & 15;
    const int quad = lane >> 4;
    f16x8 afr;
    #pragma unroll
    for (int j = 0; j < 8; ++j) {
        const int d = quad * 8 + j - mrow;
        afr[j] = (d >= 0 && d < 11) ? (_Float16)gw[d] : (_Float16)0.f;
    }
    const f32x4 z4 = {0.f, 0.f, 0.f, 0.f};

    // ---- Pass 1 (vertical): wave wv owns plane wv; 5 x-chunks. ----
    // V[m][x] = sum_k g[k-m] * raw[y=k][x];  B from swizzled rawT (2x b64).
    const int swr = mrow >> 1;           // (x>>1)&7 for x = 16c + mrow
    #pragma unroll
    for (int c = 0; c < 5; ++c) {
        const int x = c * 16 + mrow;
        const _Float16* base = &rawT[wv * 2560 + x * 32];
        union { f16x4 h[2]; f16x8 v; } bu;
        bu.h[0] = *(const f16x4*)&base[((2 * quad    ) ^ swr) << 2];
        bu.h[1] = *(const f16x4*)&base[((2 * quad + 1) ^ swr) << 2];
        const f32x4 dv = __builtin_amdgcn_mfma_f32_16x16x32_f16(afr, bu.v, z4, 0, 0, 0);
        #pragma unroll
        for (int r = 0; r < 4; ++r)
            vbuf[wv * 1408 + (quad * 4 + r) * 88 + x] = (_Float16)dv[r];
    }
    __syncthreads();

    // ---- Pass 2 (horizontal) + SSIM: wave wv owns x-tile X0 = 16*wv. ----
    float lsum = 0.f;
    {
        const int X0 = wv * 16;
        f32x4 dq[4];
        #pragma unroll
        for (int pl = 0; pl < 4; ++pl) {
            const f16x8 bv = *(const f16x8*)&vbuf[pl * 1408 + mrow * 88 + X0 + quad * 8];
            dq[pl] = __builtin_amdgcn_mfma_f32_16x16x32_f16(afr, bv, z4, 0, 0, 0);
        }
        #pragma unroll
        for (int r = 0; r < 4; ++r) {
            const float mp = dq[0][r], mt = dq[1][r];
            const float sv = dq[2][r], qv = dq[3][r];
            const float mp2 = mp * mp, mt2 = mt * mt, mpt = mp * mt;
            const float sig = fmaxf(sv - mp2 - mt2, 0.f);
            const float cv  = qv - mpt;
            const float num = (2.f * mpt + 1e-4f) * (2.f * cv + 9e-4f);
            const float den = (mp2 + mt2 + 1e-4f) * (sig + 9e-4f);
            lsum += num * __builtin_amdgcn_rcpf(den + 1e-8f);
        }
    }

    // ---- Block reduce -> one plain float store per block. ----
    #pragma unroll
    for (int off = 32; off > 0; off >>= 1)
        lsum += __shfl_down(lsum, off, 64);
    if (lane == 0) wsum[wv] = lsum;
    __syncthreads();
    if (tid == 0)
        partial[bid] = wsum[0] + wsum[1] + wsum[2] + wsum[3];
}

__global__ __launch_bounds__(256)
void ssim_reduce(const float* __restrict__ partial, float* __restrict__ out)
{
    __shared__ double ws[4];
    double s = 0.0;
    const f32x4* p4 = (const f32x4*)partial;
    for (int i = threadIdx.x; i < NBLK / 4; i += 256) {
        const f32x4 v = p4[i];
        s += (double)v[0] + (double)v[1] + (double)v[2] + (double)v[3];
    }
    #pragma unroll
    for (int off = 32; off > 0; off >>= 1)
        s += __shfl_down(s, off, 64);
    if ((threadIdx.x & 63) == 0) ws[threadIdx.x >> 6] = s;
    __syncthreads();
    if (threadIdx.x == 0) {
        const double tot = ws[0] + ws[1] + ws[2] + ws[3];
        out[0] = (float)(1.0 - tot / 8388608.0);
    }
}

extern "C" void kernel_launch(void* const* d_in, const int* in_sizes, int n_in,
                              void* d_out, int out_size, void* d_ws, size_t ws_size,
                              hipStream_t stream)
{
    const float* pred = (const float*)d_in[0];
    const float* targ = (const float*)d_in[1];
    const float* win  = (const float*)d_in[2];
    float* out     = (float*)d_out;
    float* partial = (float*)d_ws;      // NBLK floats = 32 KiB scratch

    ssim_fused<<<NBLK, 256, 0, stream>>>(pred, targ, win, partial);
    ssim_reduce<<<1, 256, 0, stream>>>(partial, out);
}